// Round 7
// baseline (1676.347 us; speedup 1.0000x reference)
//
#include <hip/hip_runtime.h>

#define Bb 128
#define Tt 24
#define Ee 512
#define Hh 512
#define Aa 512
#define Vv 20000
#define Pp 196
#define TV (Tt*Vv)
#define NBLK 512
#define NTHR 256
#define GT (NBLK*NTHR)

typedef __attribute__((ext_vector_type(8))) short bfrag;           // 8 bf16
typedef __attribute__((ext_vector_type(4))) float f4;              // MFMA acc
typedef __attribute__((ext_vector_type(4))) unsigned short us4;    // 4 bf16

#define MFMA16(a,b,c) __builtin_amdgcn_mfma_f32_16x16x32_bf16(a,b,c,0,0,0)

__device__ __forceinline__ unsigned short f2bf(float f){
  unsigned int x = __builtin_bit_cast(unsigned int, f);
  x += 0x7fffu + ((x >> 16) & 1u);   // RTNE
  return (unsigned short)(x >> 16);
}
__device__ __forceinline__ float bfu2f(unsigned short u){
  unsigned int x = ((unsigned int)u) << 16;
  return __builtin_bit_cast(float, x);
}
#define LOG2E 1.442695041f
__device__ __forceinline__ float fexp2(float x){ return __builtin_amdgcn_exp2f(x); }
__device__ __forceinline__ float frcp (float x){ return __builtin_amdgcn_rcpf(x); }
__device__ __forceinline__ float tanh_f(float x){ return 1.0f - 2.0f*frcp(1.0f + fexp2((2.0f*LOG2E)*x)); }
__device__ __forceinline__ float sigm_f(float x){ return frcp(1.0f + fexp2(-LOG2E*x)); }

// ---- device-coherent access ----
__device__ __forceinline__ unsigned long long scld8(const void* p){
  return __hip_atomic_load((const unsigned long long*)p, __ATOMIC_RELAXED, __HIP_MEMORY_SCOPE_AGENT);
}
__device__ __forceinline__ unsigned scld4(const unsigned* p){
  return __hip_atomic_load(p, __ATOMIC_RELAXED, __HIP_MEMORY_SCOPE_AGENT);
}
__device__ __forceinline__ void scst4(unsigned* p, unsigned v){
  __hip_atomic_store(p, v, __ATOMIC_RELAXED, __HIP_MEMORY_SCOPE_AGENT);
}

// ---- flags: 64B lines, monotone generation values ----
__device__ __forceinline__ void set_flag(unsigned* line, unsigned v){
  asm volatile("s_waitcnt vmcnt(0)" ::: "memory");
  __syncthreads();
  if(threadIdx.x == 0) scst4(line, v);
}
__device__ __forceinline__ void poll_flags(const unsigned* base, int n, unsigned tgt){
  int tid = threadIdx.x;
  for(;;){
    int ok = (tid < n) ? (scld4(base + tid*16) >= tgt) : 1;
    if(__syncthreads_count(ok) == NTHR) break;
    __builtin_amdgcn_s_sleep(4);
  }
  asm volatile("" ::: "memory");
}

// ---- prep grid barrier: 32 split counters + leader-published generation ----
__device__ __forceinline__ void gbar2(unsigned* sync, unsigned phase){
  __syncthreads();
  int tid = threadIdx.x, blk = blockIdx.x;
  if(tid == 0)
    (void)__hip_atomic_fetch_add(sync + (blk & 31)*16, 1u,
                                 __ATOMIC_RELEASE, __HIP_MEMORY_SCOPE_AGENT);
  if(blk == 0){
    for(;;){
      int ok = (tid < 32) ? (scld4(sync + tid*16) >= phase*16u) : 1;
      if(__syncthreads_count(ok) == NTHR) break;
      __builtin_amdgcn_s_sleep(2);
    }
    if(tid == 0) scst4(sync + 32*16, phase);
  }
  if(tid == 0){
    while(scld4(sync + 32*16) < phase) __builtin_amdgcn_s_sleep(2);
    (void)__hip_atomic_load(sync + 32*16, __ATOMIC_ACQUIRE, __HIP_MEMORY_SCOPE_AGENT);
  }
  __syncthreads();
}

__global__ void k_zero(unsigned* s){
  int i = blockIdx.x*256 + threadIdx.x;
  s[i] = 0u;
}

// ---------------- prep helpers (verified) ----------------
__device__ __forceinline__ void cast_loop(const float* __restrict__ s,
                                          unsigned short* __restrict__ d,
                                          int n4, int gtid){
  for(int i = gtid; i < n4; i += GT){
    float4 v = ((const float4*)s)[i];
    us4 o; o[0]=f2bf(v.x); o[1]=f2bf(v.y); o[2]=f2bf(v.z); o[3]=f2bf(v.w);
    ((us4*)d)[i] = o;
  }
}
__device__ __forceinline__ void tr_tile(const float* __restrict__ S,
                                        unsigned short* __restrict__ D,
                                        int it, int jt, int tid, float (*T)[33]){
  int er = tid>>3, c4 = (tid&7)*4;
  float4 v = *(const float4*)(S + (size_t)(jt*32+er)*512 + it*32 + c4);
  T[er][c4+0]=v.x; T[er][c4+1]=v.y; T[er][c4+2]=v.z; T[er][c4+3]=v.w;
  __syncthreads();
  us4 o;
  o[0]=f2bf(T[c4+0][er]); o[1]=f2bf(T[c4+1][er]);
  o[2]=f2bf(T[c4+2][er]); o[3]=f2bf(T[c4+3][er]);
  *(us4*)(D + (size_t)(it*32+er)*512 + jt*32 + c4) = o;
  __syncthreads();
}

// ---------------- LDS bulk staging (coherent -> LDS, one latency exposure) ----------------
// 16 rows x 512 bf16 (16 KB), XOR-swizzled: byte ^= (row&7)<<4
__device__ __forceinline__ void stage16(char* dstSM, const unsigned short* src, int R0){
  int tid = threadIdx.x;
  #pragma unroll
  for(int j=0;j<8;j++){
    int u = tid + j*256;              // 2048 8B units
    int row = u >> 7, c8 = u & 127;
    unsigned long long q = scld8(src + (size_t)(R0+row)*Hh + c8*4);
    int bo = (row<<10) + (c8<<3);
    bo ^= (row&7)<<4;
    *(unsigned long long*)(dstSM + bo) = q;
  }
}

// ---------------- step tasks ----------------

// attention for row b: stage h[b], hproj (VALU), scores, softmax, ctx
__device__ void attention_task(int b, const unsigned short* __restrict__ hbU_t,
                               const unsigned short* __restrict__ WhT, const float* __restrict__ bhv,
                               const unsigned short* __restrict__ fpb,
                               const unsigned short* __restrict__ featsB,
                               const float* __restrict__ vatt,
                               unsigned short* __restrict__ ctx_t, char* SM)
{
  float* h_s = (float*)SM;          // 512
  float* hp  = h_s + 512;           // permuted hp[(a&31)*16 + (a>>5)]
  float* vp  = hp + 512;
  float* sc  = vp + 512;
  float* red = sc + 200;
  int tid = threadIdx.x;
  if(tid < 128){
    unsigned long long q8 = scld8(hbU_t + (size_t)b*Hh + tid*4);
    h_s[tid*4+0] = bfu2f((unsigned short)(q8));
    h_s[tid*4+1] = bfu2f((unsigned short)(q8>>16));
    h_s[tid*4+2] = bfu2f((unsigned short)(q8>>32));
    h_s[tid*4+3] = bfu2f((unsigned short)(q8>>48));
  }
  { float2 vv = *(const float2*)(vatt + tid*2);
    int a0=tid*2, a1=a0+1;
    vp[((a0&31)<<4)+(a0>>5)] = vv.x;
    vp[((a1&31)<<4)+(a1>>5)] = vv.y; }
  __syncthreads();
  // hproj[a] = bh[a] + sum_k h[k]*Wh[k,a]  (verified round-3 path)
  for(int rep=0;rep<2;rep++){
    int a = tid + rep*256;
    float s = bhv[a];
    const unsigned short* wr = WhT + (size_t)a*Hh;
    for(int k=0;k<Hh;k+=8){
      bfrag wv = *(const bfrag*)(wr + k);
      #pragma unroll
      for(int q=0;q<8;q++) s += h_s[k+q] * bfu2f((unsigned short)wv[q]);
    }
    hp[((a&31)<<4)+(a>>5)] = s;
  }
  __syncthreads();
  int grp = tid >> 4, gl = tid & 15;
  for(int pass=0; pass<13; pass++){
    int p = pass*16 + grp;
    float acc = 0.0f;
    if(p < Pp){
      const unsigned short* fr = fpb + ((size_t)b*Pp + p)*Aa + gl*32;
      #pragma unroll
      for(int j=0;j<32;j+=8){
        bfrag fv = *(const bfrag*)(fr + j);
        #pragma unroll
        for(int q=0;q<8;q++){
          int idx = ((j+q)<<4) + gl;
          float x = bfu2f((unsigned short)fv[q]) + hp[idx];
          acc += tanh_f(x) * vp[idx];
        }
      }
    }
    acc += __shfl_xor(acc, 1, 64);
    acc += __shfl_xor(acc, 2, 64);
    acc += __shfl_xor(acc, 4, 64);
    acc += __shfl_xor(acc, 8, 64);
    if(p < Pp && gl == 0) sc[p] = acc;
  }
  __syncthreads();
  if(tid < 64){
    float m = -1e30f;
    for(int i=0;i<4;i++){ int p = tid + i*64; if(p < Pp) m = fmaxf(m, sc[p]); }
    for(int off=1; off<64; off<<=1) m = fmaxf(m, __shfl_xor(m, off, 64));
    float s = 0.0f;
    for(int i=0;i<4;i++){ int p = tid + i*64; if(p < Pp) s += fexp2((sc[p]-m)*LOG2E); }
    for(int off=1; off<64; off<<=1) s += __shfl_xor(s, off, 64);
    if(tid == 0){ red[0] = m; red[1] = frcp(s); }
  }
  __syncthreads();
  float mx = red[0], rS = red[1];
  float al_t = 0.0f;
  if(tid < Pp) al_t = fexp2((sc[tid]-mx)*LOG2E) * rS;
  __syncthreads();
  if(tid < Pp) sc[tid] = al_t;
  __syncthreads();
  float c0 = 0.f, c1 = 0.f;
  const unsigned int* fb = (const unsigned int*)(featsB + (size_t)b*Pp*Ee);
  for(int p=0;p<Pp;p++){
    float al = sc[p];
    unsigned int u = fb[(size_t)p*256 + tid];
    unsigned int lo = (u & 0xffffu) << 16, hi = u & 0xffff0000u;
    c0 += al * __builtin_bit_cast(float, lo);
    c1 += al * __builtin_bit_cast(float, hi);
  }
  unsigned int cw = ((unsigned int)f2bf(c1) << 16) | (unsigned int)f2bf(c0);
  scst4((unsigned*)ctx_t + (size_t)b*256 + tid, cw);
}

// gates phase A: agh = h@Whh^T, agi = emb@Wih[:,0:512]^T  (A from LDS / cached global)
__device__ void gates_phaseA(int R0, int HC0, const unsigned short* __restrict__ eseqT,
                             const unsigned short* __restrict__ WihB,
                             const unsigned short* __restrict__ WhhB,
                             const char* SMh, f4 (&agh)[3], f4 (&agi)[3])
{
  int tid = threadIdx.x;
  int w = tid>>6, l = tid&63, l16 = l&15, lk = l>>4;
  int hcol = HC0 + w*16 + l16;
  #pragma unroll
  for(int q=0;q<3;q++){ agh[q]=(f4)(0.f); agi[q]=(f4)(0.f); }
  for(int k0=0;k0<512;k0+=32){
    int koff = k0 + lk*8;
    int bo = (l16<<10) + (koff<<1); bo ^= (l16&7)<<4;
    bfrag ah = *(const bfrag*)(SMh + bo);
    bfrag ae = *(const bfrag*)(eseqT + (size_t)(R0+l16)*Ee + koff);
    #pragma unroll
    for(int q=0;q<3;q++){
      int j = q*512 + hcol;
      bfrag bh_ = *(const bfrag*)(WhhB + (size_t)j*512  + koff);
      bfrag be  = *(const bfrag*)(WihB + (size_t)j*1024 + koff);
      agh[q] = MFMA16(ah, bh_, agh[q]);
      agi[q] = MFMA16(ae, be,  agi[q]);
    }
  }
}

// gates phase B: agi += ctx@Wih[:,512:1024]^T; gate math; h_new writes
__device__ void gates_phaseB(int R0, int HC0, const char* SMc,
                             const unsigned short* __restrict__ WihB,
                             const float* __restrict__ bih, const float* __restrict__ bhh,
                             const float* __restrict__ hf_cur, float* __restrict__ hf_nxt,
                             unsigned short* __restrict__ hbU_nxt,
                             f4 (&agh)[3], f4 (&agi)[3], char* SM_HB)
{
  int tid = threadIdx.x;
  int w = tid>>6, l = tid&63, l16 = l&15, lk = l>>4;
  int hcol = HC0 + w*16 + l16;
  for(int k0=0;k0<512;k0+=32){
    int koff = k0 + lk*8;
    int bo = (l16<<10) + (koff<<1); bo ^= (l16&7)<<4;
    bfrag ac = *(const bfrag*)(SMc + bo);
    #pragma unroll
    for(int q=0;q<3;q++){
      int j = q*512 + hcol;
      bfrag bc = *(const bfrag*)(WihB + (size_t)j*1024 + 512 + koff);
      agi[q] = MFMA16(ac, bc, agi[q]);
    }
  }
  float bir = bih[hcol],      bhr = bhh[hcol];
  float biz = bih[512+hcol],  bhz = bhh[512+hcol];
  float bin = bih[1024+hcol], bhn = bhh[1024+hcol];
  unsigned short (*HB)[64] = (unsigned short(*)[64])SM_HB;
  #pragma unroll
  for(int i=0;i<4;i++){
    int row = lk*4 + i;
    int b = R0 + row;
    float r_ = sigm_f(agi[0][i] + bir + agh[0][i] + bhr);
    float z_ = sigm_f(agi[1][i] + biz + agh[1][i] + bhz);
    float n_ = tanh_f(agi[2][i] + bin + r_*(agh[2][i] + bhn));
    float ho = hf_cur[(size_t)b*Hh + hcol];
    float hn = (1.0f - z_)*n_ + z_*ho;
    hf_nxt[(size_t)b*Hh + hcol] = hn;       // block-private slice across steps
    HB[row][w*16 + l16] = f2bf(hn);
  }
  __syncthreads();
  #pragma unroll
  for(int j=0;j<2;j++){
    int widx = tid + j*256;                 // 0..511 words: 16 rows x 32 word-pairs
    int row = widx >> 5, pr = widx & 31;
    unsigned uu = (unsigned)HB[row][pr*2] | ((unsigned)HB[row][pr*2+1] << 16);
    scst4((unsigned*)(hbU_nxt + (size_t)(R0+row)*Hh + HC0) + pr, uu);
  }
}

// pred tile: 64 b-rows x 128 v-cols; h staged into XOR-swizzled LDS (verified)
__device__ void pred_task(int pt, int tw, const unsigned short* __restrict__ hb_cur,
                          const unsigned short* __restrict__ WoutB,
                          const float* __restrict__ bout, float* __restrict__ out,
                          char* SM)
{
  int tid = threadIdx.x;
  int vchunk = pt >> 1, mbase = (pt & 1)*64;
  for(int j=0;j<32;j++){
    int u = tid + j*256;
    int row = u >> 7, c8 = u & 127;
    unsigned long long q = scld8(hb_cur + (size_t)(mbase+row)*Hh + c8*4);
    int bo = (row<<10) + (c8<<3);
    bo ^= (row&7)<<4;
    *(unsigned long long*)(SM + bo) = q;
  }
  __syncthreads();
  int w = tid>>6, l = tid&63, l16 = l&15, lk = l>>4;
  int nb = vchunk*128 + w*32;
  f4 acc[4][2];
  #pragma unroll
  for(int mi=0;mi<4;mi++) for(int ni=0;ni<2;ni++) acc[mi][ni] = (f4)(0.0f);
  for(int k0=0;k0<512;k0+=32){
    int koff = k0 + lk*8;
    bfrag af[4], bq[2];
    #pragma unroll
    for(int mi=0;mi<4;mi++){
      int row = mi*16 + l16;
      int bo = (row<<10) + (koff<<1);
      bo ^= (row&7)<<4;
      af[mi] = *(const bfrag*)(SM + bo);
    }
    #pragma unroll
    for(int ni=0;ni<2;ni++){
      int v = nb + ni*16 + l16; if(v > Vv-1) v = Vv-1;
      bq[ni] = *(const bfrag*)(WoutB + (size_t)v*Hh + koff);
    }
    #pragma unroll
    for(int mi=0;mi<4;mi++)
      #pragma unroll
      for(int ni=0;ni<2;ni++)
        acc[mi][ni] = MFMA16(af[mi], bq[ni], acc[mi][ni]);
  }
  #pragma unroll
  for(int ni=0;ni<2;ni++){
    int v = nb + ni*16 + l16;
    if(v < Vv){
      float bias = bout[v];
      #pragma unroll
      for(int mi=0;mi<4;mi++){
        #pragma unroll
        for(int i=0;i<4;i++){
          int br = mbase + mi*16 + lk*4 + i;
          __builtin_nontemporal_store(acc[mi][ni][i] + bias,
              out + (size_t)br*TV + (size_t)tw*Vv + v);
        }
      }
    }
  }
  __syncthreads();
}

// ---------------- the persistent kernel ----------------
// sync lines: [0..31] gbar ctrs, [32] gen, [40..167] flagsA(b),
// [168..231] flagsG(r*8+c), [240..247] aggP(xcd)
__global__ __launch_bounds__(NTHR, 2) void k_all(
    const float* feats, const int* caps, const float* emb,
    const float* Winh, const float* binh, const float* Wino, const float* bino,
    const float* Wf, const float* bfv, const float* Wh, const float* bhv,
    const float* vatt, const float* Wih, const float* Whh,
    const float* bih, const float* bhh, const float* Wout, const float* bout,
    float* out,
    float* hfR, unsigned short* hbU,
    unsigned short* ctxR, unsigned short* avgB, unsigned short* eseq,
    unsigned short* WfT, unsigned short* WhT,
    unsigned short* WinhT, unsigned short* WinoT,
    unsigned short* WihB, unsigned short* WhhB,
    unsigned short* fpb, unsigned short* featsB, unsigned short* WoutB,
    unsigned* sync)
{
  __shared__ char SMEM[65536];
  const int blk = blockIdx.x, tid = threadIdx.x;
  const int gtid = blk*NTHR + tid;
  unsigned* flagsA = sync + 40*16;
  unsigned* flagsG = sync + 168*16;
  unsigned* aggP   = sync + 240*16;
  float* h_f0 = hfR;
  unsigned short* h_b0 = hbU;            // ring slot 0

  // ================= P0 =================
  cast_loop(Wih,  WihB,  (3*Hh*2*Ee)/4, gtid);
  cast_loop(Whh,  WhhB,  (3*Hh*Hh)/4,   gtid);
  cast_loop(Wout, WoutB, (Vv*Hh)/4,     gtid);
  cast_loop(feats,featsB,(Bb*Pp*Ee)/4,  gtid);
  for(int task = blk; task < 1024; task += NBLK){
    int z = task >> 8, rt = task & 255;
    int it = rt & 15, jt = rt >> 4;
    const float* S = (z==0)?Wf:(z==1)?Wh:(z==2)?Winh:Wino;
    unsigned short* D = (z==0)?WfT:(z==1)?WhT:(z==2)?WinhT:WinoT;
    tr_tile(S, D, it, jt, tid, (float(*)[33])SMEM);
  }
  if(blk < Bb){
    int b = blk;
    const float* fb = feats + (size_t)b*Pp*Ee;
    float a0=0.f, a1=0.f;
    for(int p=0;p<Pp;p++){
      float2 v = *(const float2*)(fb + (size_t)p*Ee + tid*2);
      a0 += v.x; a1 += v.y;
    }
    a0 *= (1.0f/Pp); a1 *= (1.0f/Pp);
    unsigned int pack = ((unsigned int)f2bf(a1)<<16) | (unsigned int)f2bf(a0);
    ((unsigned int*)avgB)[(size_t)b*256 + tid] = pack;
  }
  for(int task = blk; task < (Tt-1)*Bb; task += NBLK){
    int ts = task/Bb + 1, b = task%Bb;
    int cap = caps[b*Tt + (ts-1)];
    float2 v = *(const float2*)(emb + (size_t)cap*Ee + tid*2);
    unsigned int pack = ((unsigned int)f2bf(v.y)<<16) | (unsigned int)f2bf(v.x);
    ((unsigned int*)(eseq + ((size_t)ts*Bb + b)*Ee))[tid] = pack;
  }
  gbar2(sync, 1);

  // ================= P1: featproj + initproj =================
  for(int task = blk; task < 1584; task += NBLK){
    int w = tid>>6, l = tid&63, l16 = l&15, lk = l>>4;
    if(task < 1568){
      int bx = task % 196, by = task / 196;
      size_t m_base = (size_t)bx*128 + (w&1)*64;
      int nb = by*64 + (w>>1)*32;
      f4 acc[4][2];
      #pragma unroll
      for(int mi=0;mi<4;mi++) for(int ni=0;ni<2;ni++) acc[mi][ni] = (f4)(0.0f);
      for(int k0=0;k0<512;k0+=32){
        int koff = k0 + lk*8;
        bfrag af[4], bq[2];
        #pragma unroll
        for(int mi=0;mi<4;mi++) af[mi] = *(const bfrag*)(featsB + (m_base+mi*16+l16)*512 + koff);
        #pragma unroll
        for(int ni=0;ni<2;ni++) bq[ni] = *(const bfrag*)(WfT + (size_t)(nb+ni*16+l16)*512 + koff);
        #pragma unroll
        for(int mi=0;mi<4;mi++)
          #pragma unroll
          for(int ni=0;ni<2;ni++)
            acc[mi][ni] = MFMA16(af[mi], bq[ni], acc[mi][ni]);
      }
      #pragma unroll
      for(int ni=0;ni<2;ni++){
        int a = nb + ni*16 + l16;
        float bias = bfv[a];
        #pragma unroll
        for(int mi=0;mi<4;mi++){
          size_t r = m_base + mi*16 + lk*4;
          #pragma unroll
          for(int i=0;i<4;i++)
            fpb[(r+i)*512 + a] = f2bf(acc[mi][ni][i] + bias);
        }
      }
    } else {
      int idx = task - 1568;
      int y = idx >> 3, xb = idx & 7;
      int m0 = (w&1)*64, nb = xb*64 + (w>>1)*32;
      const unsigned short* Wt = y ? WinoT : WinhT;
      const float* bias = y ? bino : binh;
      f4 acc[4][2];
      #pragma unroll
      for(int mi=0;mi<4;mi++) for(int ni=0;ni<2;ni++) acc[mi][ni] = (f4)(0.0f);
      for(int k0=0;k0<512;k0+=32){
        int koff = k0 + lk*8;
        bfrag af[4], bq[2];
        #pragma unroll
        for(int mi=0;mi<4;mi++) af[mi] = *(const bfrag*)(avgB + (size_t)(m0+mi*16+l16)*512 + koff);
        #pragma unroll
        for(int ni=0;ni<2;ni++) bq[ni] = *(const bfrag*)(Wt + (size_t)(nb+ni*16+l16)*512 + koff);
        #pragma unroll
        for(int mi=0;mi<4;mi++)
          #pragma unroll
          for(int ni=0;ni<2;ni++)
            acc[mi][ni] = MFMA16(af[mi], bq[ni], acc[mi][ni]);
      }
      #pragma unroll
      for(int ni=0;ni<2;ni++){
        int n = nb + ni*16 + l16;
        float bv = bias[n];
        #pragma unroll
        for(int mi=0;mi<4;mi++){
          int bb = m0 + mi*16 + lk*4;
          #pragma unroll
          for(int i=0;i<4;i++){
            float val = tanh_f(acc[mi][ni][i] + bv);
            if(y==0){ h_f0[(size_t)(bb+i)*Hh + n] = val; h_b0[(size_t)(bb+i)*Hh + n] = f2bf(val); }
            else    { eseq[(size_t)(bb+i)*Ee + n] = f2bf(val); }
          }
        }
      }
    }
  }
  gbar2(sync, 2);

  // ================= step loop =================
  int xcd = blk & 7, slot = blk >> 3;

  if(slot < 16){
    // ---- attention role: b = slot*8 + xcd ----
    int b = slot*8 + xcd;
    int rg = b >> 4;                       // row group
    for(int t=0; t<Tt; t++){
      if(t > 0) poll_flags(flagsG + rg*8*16, 8, (unsigned)t);
      attention_task(b, hbU + (size_t)t*Bb*Hh, WhT, bhv, fpb, featsB, vatt,
                     ctxR + (size_t)(t&3)*Bb*Ee, SMEM);
      set_flag(flagsA + b*16, (unsigned)(t+1));
    }
  } else if(slot < 24){
    // ---- gates role: r = slot-16 (rows), c = xcd (cols) ----
    int r = slot - 16, c = xcd;
    int R0 = r*16, HC0 = c*64;
    char* SMh = SMEM;            // 16 KB
    char* SMc = SMEM + 16384;    // 16 KB
    char* SMB = SMEM + 32768;    // HB 2 KB
    f4 agh[3], agi[3];
    stage16(SMh, hbU, R0);                              // h(0) from L3 (post-barrier)
    __syncthreads();
    gates_phaseA(R0, HC0, eseq, WihB, WhhB, SMh, agh, agi);
    for(int t=0; t<Tt; t++){
      poll_flags(flagsA + R0*16, 16, (unsigned)(t+1));
      stage16(SMc, ctxR + (size_t)(t&3)*Bb*Ee, R0);
      __syncthreads();
      gates_phaseB(R0, HC0, SMc, WihB, bih, bhh,
                   hfR + (size_t)(t&1)*Bb*Hh, hfR + (size_t)((t+1)&1)*Bb*Hh,
                   hbU + (size_t)(t+1)*Bb*Hh, agh, agi, SMB);
      set_flag(flagsG + (r*8+c)*16, (unsigned)(t+1));
      if(t+1 < Tt){
        poll_flags(flagsG + r*8*16, 8, (unsigned)(t+1));
        stage16(SMh, hbU + (size_t)(t+1)*Bb*Hh, R0);
        __syncthreads();
        gates_phaseA(R0, HC0, eseq + (size_t)(t+1)*Bb*Ee, WihB, WhhB, SMh, agh, agi);
      }
    }
  } else {
    // ---- pred role ----
    int ps = slot - 24;                    // 0..39
    int pt = xcd*40 + ps;
    if(ps == 0){
      // aggregator + worker (one per xcd-group)
      for(int t=1; t<=Tt; t++){
        poll_flags(flagsG, 64, (unsigned)t);
        if(tid == 0) scst4(aggP + xcd*16, (unsigned)t);
        pred_task(pt, t-1, hbU + (size_t)t*Bb*Hh, WoutB, bout, out, SMEM);
      }
    } else if(pt < 314){
      for(int t=1; t<=Tt; t++){
        poll_flags(aggP + xcd*16, 1, (unsigned)t);
        pred_task(pt, t-1, hbU + (size_t)t*Bb*Hh, WoutB, bout, out, SMEM);
      }
    }
  }
}

extern "C" void kernel_launch(void* const* d_in, const int* in_sizes, int n_in,
                              void* d_out, int out_size, void* d_ws, size_t ws_size,
                              hipStream_t stream)
{
  const float* feats = (const float*)d_in[0];
  const int*   caps  = (const int*)d_in[1];
  const float* emb   = (const float*)d_in[2];
  const float* Winh  = (const float*)d_in[3];
  const float* binh  = (const float*)d_in[4];
  const float* Wino  = (const float*)d_in[5];
  const float* bino  = (const float*)d_in[6];
  const float* Wf    = (const float*)d_in[7];
  const float* bfv   = (const float*)d_in[8];
  const float* Wh    = (const float*)d_in[9];
  const float* bhv   = (const float*)d_in[10];
  const float* vatt  = (const float*)d_in[11];
  const float* Wih   = (const float*)d_in[12];
  const float* Whh   = (const float*)d_in[13];
  const float* bih   = (const float*)d_in[14];
  const float* bhh   = (const float*)d_in[15];
  const float* Wout  = (const float*)d_in[16];
  const float* bout  = (const float*)d_in[17];
  float* out = (float*)d_out;

  char* ws = (char*)d_ws;
  size_t off = 0;
  auto alloc = [&](size_t bytes){
    off = (off + 255) & ~(size_t)255;
    void* p = ws + off; off += bytes; return p;
  };
  unsigned* syncp = (unsigned*)alloc(16384);
  float* hfR = (float*)alloc((size_t)2*Bb*Hh*4);                        // hf ring (2)
  unsigned short* hbU = (unsigned short*)alloc((size_t)(Tt+1)*Bb*Hh*2); // h ring (25)
  unsigned short* ctxR  = (unsigned short*)alloc((size_t)4*Bb*Ee*2);    // ctx ring (4)
  unsigned short* avgB  = (unsigned short*)alloc((size_t)Bb*Ee*2);
  unsigned short* eseq  = (unsigned short*)alloc((size_t)Tt*Bb*Ee*2);
  unsigned short* WfT   = (unsigned short*)alloc((size_t)Ee*Aa*2);
  unsigned short* WhT   = (unsigned short*)alloc((size_t)Hh*Aa*2);
  unsigned short* WinhT = (unsigned short*)alloc((size_t)Ee*Hh*2);
  unsigned short* WinoT = (unsigned short*)alloc((size_t)Ee*Hh*2);
  unsigned short* WihB  = (unsigned short*)alloc((size_t)3*Hh*2*Ee*2);
  unsigned short* WhhB  = (unsigned short*)alloc((size_t)3*Hh*Hh*2);
  unsigned short* fpb   = (unsigned short*)alloc((size_t)Bb*Pp*Aa*2);
  unsigned short* featsB= (unsigned short*)alloc((size_t)Bb*Pp*Ee*2);
  unsigned short* WoutB = (unsigned short*)alloc((size_t)Vv*Hh*2);
  if(ws_size < off) return;   // diagnostic no-op

  k_zero<<<16, 256, 0, stream>>>(syncp);
  k_all<<<NBLK, NTHR, 0, stream>>>(
      feats, caps, emb, Winh, binh, Wino, bino, Wf, bfv, Wh, bhv, vatt,
      Wih, Whh, bih, bhh, Wout, bout, out,
      hfR, hbU, ctxR, avgB, eseq,
      WfT, WhT, WinhT, WinoT, WihB, WhhB, fpb, featsB, WoutB, syncp);
}

// Round 8
// 1439.376 us; speedup vs baseline: 1.1646x; 1.1646x over previous
//
#include <hip/hip_runtime.h>

#define Bb 128
#define Tt 24
#define Ee 512
#define Hh 512
#define Aa 512
#define Vv 20000
#define Pp 196
#define TV (Tt*Vv)
#define NBLK 512
#define NTHR 256
#define GT (NBLK*NTHR)
#define SMEM_BYTES 34816

typedef __attribute__((ext_vector_type(8))) short bfrag;           // 8 bf16
typedef __attribute__((ext_vector_type(4))) float f4;              // MFMA acc
typedef __attribute__((ext_vector_type(4))) unsigned short us4;    // 4 bf16

#define MFMA16(a,b,c) __builtin_amdgcn_mfma_f32_16x16x32_bf16(a,b,c,0,0,0)

__device__ __forceinline__ unsigned short f2bf(float f){
  unsigned int x = __builtin_bit_cast(unsigned int, f);
  x += 0x7fffu + ((x >> 16) & 1u);   // RTNE
  return (unsigned short)(x >> 16);
}
__device__ __forceinline__ float bfu2f(unsigned short u){
  unsigned int x = ((unsigned int)u) << 16;
  return __builtin_bit_cast(float, x);
}
#define LOG2E 1.442695041f
__device__ __forceinline__ float fexp2(float x){ return __builtin_amdgcn_exp2f(x); }
__device__ __forceinline__ float frcp (float x){ return __builtin_amdgcn_rcpf(x); }
__device__ __forceinline__ float tanh_f(float x){ return 1.0f - 2.0f*frcp(1.0f + fexp2((2.0f*LOG2E)*x)); }
__device__ __forceinline__ float sigm_f(float x){ return frcp(1.0f + fexp2(-LOG2E*x)); }

// ---- device-coherent access ----
__device__ __forceinline__ unsigned long long scld8(const void* p){
  return __hip_atomic_load((const unsigned long long*)p, __ATOMIC_RELAXED, __HIP_MEMORY_SCOPE_AGENT);
}
__device__ __forceinline__ unsigned scld4(const unsigned* p){
  return __hip_atomic_load(p, __ATOMIC_RELAXED, __HIP_MEMORY_SCOPE_AGENT);
}
__device__ __forceinline__ void scst4(unsigned* p, unsigned v){
  __hip_atomic_store(p, v, __ATOMIC_RELAXED, __HIP_MEMORY_SCOPE_AGENT);
}
__device__ __forceinline__ void scstf(float* p, float v){
  __hip_atomic_store(p, v, __ATOMIC_RELAXED, __HIP_MEMORY_SCOPE_AGENT);
}

// ---- flags: 64B lines, monotone generation values ----
__device__ __forceinline__ void set_flag(unsigned* line, unsigned v){
  asm volatile("s_waitcnt vmcnt(0)" ::: "memory");
  __syncthreads();
  if(threadIdx.x == 0) scst4(line, v);
}
__device__ __forceinline__ void poll_flags(const unsigned* base, int n, unsigned tgt){
  int tid = threadIdx.x;
  for(;;){
    int ok = (tid < n) ? (scld4(base + tid*16) >= tgt) : 1;
    if(__syncthreads_count(ok) == NTHR) break;
    __builtin_amdgcn_s_sleep(4);
  }
  asm volatile("" ::: "memory");
}

// ---- prep grid barrier: 32 split counters + leader-published generation ----
__device__ __forceinline__ void gbar2(unsigned* sync, unsigned phase){
  __syncthreads();
  int tid = threadIdx.x, blk = blockIdx.x;
  if(tid == 0)
    (void)__hip_atomic_fetch_add(sync + (blk & 31)*16, 1u,
                                 __ATOMIC_RELEASE, __HIP_MEMORY_SCOPE_AGENT);
  if(blk == 0){
    for(;;){
      int ok = (tid < 32) ? (scld4(sync + tid*16) >= phase*16u) : 1;
      if(__syncthreads_count(ok) == NTHR) break;
      __builtin_amdgcn_s_sleep(2);
    }
    if(tid == 0) scst4(sync + 32*16, phase);
  }
  if(tid == 0){
    while(scld4(sync + 32*16) < phase) __builtin_amdgcn_s_sleep(2);
    (void)__hip_atomic_load(sync + 32*16, __ATOMIC_ACQUIRE, __HIP_MEMORY_SCOPE_AGENT);
  }
  __syncthreads();
}

__global__ void k_zero(unsigned* s){
  int i = blockIdx.x*256 + threadIdx.x;
  s[i] = 0u;
}

// ---------------- prep helpers (verified) ----------------
__device__ __forceinline__ void cast_loop(const float* __restrict__ s,
                                          unsigned short* __restrict__ d,
                                          int n4, int gtid){
  for(int i = gtid; i < n4; i += GT){
    float4 v = ((const float4*)s)[i];
    us4 o; o[0]=f2bf(v.x); o[1]=f2bf(v.y); o[2]=f2bf(v.z); o[3]=f2bf(v.w);
    ((us4*)d)[i] = o;
  }
}
__device__ __forceinline__ void tr_tile(const float* __restrict__ S,
                                        unsigned short* __restrict__ D,
                                        int it, int jt, int tid, float (*T)[33]){
  int er = tid>>3, c4 = (tid&7)*4;
  float4 v = *(const float4*)(S + (size_t)(jt*32+er)*512 + it*32 + c4);
  T[er][c4+0]=v.x; T[er][c4+1]=v.y; T[er][c4+2]=v.z; T[er][c4+3]=v.w;
  __syncthreads();
  us4 o;
  o[0]=f2bf(T[c4+0][er]); o[1]=f2bf(T[c4+1][er]);
  o[2]=f2bf(T[c4+2][er]); o[3]=f2bf(T[c4+3][er]);
  *(us4*)(D + (size_t)(it*32+er)*512 + jt*32 + c4) = o;
  __syncthreads();
}

// ---------------- LDS bulk staging (coherent -> LDS, one latency exposure) ----------------
// 16 rows x 512 bf16 (16 KB), XOR-swizzled: byte ^= (row&7)<<4
__device__ __forceinline__ void stage16(char* dstSM, const unsigned short* src, int R0){
  int tid = threadIdx.x;
  #pragma unroll
  for(int j=0;j<8;j++){
    int u = tid + j*256;              // 2048 8B units
    int row = u >> 7, c8 = u & 127;
    unsigned long long q = scld8(src + (size_t)(R0+row)*Hh + c8*4);
    int bo = (row<<10) + (c8<<3);
    bo ^= (row&7)<<4;
    *(unsigned long long*)(dstSM + bo) = q;
  }
}

// ---------------- step tasks ----------------

// attention for row b (hproj precomputed in hpr slot, bias included)
__device__ void attention_task(int b, const float* __restrict__ hpr_t,
                               const unsigned short* __restrict__ fpb,
                               const unsigned short* __restrict__ featsB,
                               const float* __restrict__ vatt,
                               unsigned short* __restrict__ ctx_t, char* SM)
{
  float* hp  = (float*)SM;          // 512, permuted hp[(a&31)*16 + (a>>5)]
  float* vp  = hp + 512;
  float* sc  = vp + 512;
  float* red = sc + 200;
  int tid = threadIdx.x;
  {
    unsigned long long q = scld8(hpr_t + (size_t)b*Aa + tid*2);
    float2 hv = __builtin_bit_cast(float2, q);
    float2 vv = *(const float2*)(vatt + tid*2);
    int a0 = tid*2, a1 = a0+1;
    hp[((a0&31)<<4)+(a0>>5)] = hv.x;
    hp[((a1&31)<<4)+(a1>>5)] = hv.y;
    vp[((a0&31)<<4)+(a0>>5)] = vv.x;
    vp[((a1&31)<<4)+(a1>>5)] = vv.y;
  }
  __syncthreads();
  int grp = tid >> 4, gl = tid & 15;
  for(int pass=0; pass<13; pass++){
    int p = pass*16 + grp;
    float acc = 0.0f;
    if(p < Pp){
      const unsigned short* fr = fpb + ((size_t)b*Pp + p)*Aa + gl*32;
      #pragma unroll
      for(int j=0;j<32;j+=8){
        bfrag fv = *(const bfrag*)(fr + j);
        #pragma unroll
        for(int q=0;q<8;q++){
          int idx = ((j+q)<<4) + gl;
          float x = bfu2f((unsigned short)fv[q]) + hp[idx];
          acc += tanh_f(x) * vp[idx];
        }
      }
    }
    acc += __shfl_xor(acc, 1, 64);
    acc += __shfl_xor(acc, 2, 64);
    acc += __shfl_xor(acc, 4, 64);
    acc += __shfl_xor(acc, 8, 64);
    if(p < Pp && gl == 0) sc[p] = acc;
  }
  __syncthreads();
  if(tid < 64){
    float m = -1e30f;
    for(int i=0;i<4;i++){ int p = tid + i*64; if(p < Pp) m = fmaxf(m, sc[p]); }
    for(int off=1; off<64; off<<=1) m = fmaxf(m, __shfl_xor(m, off, 64));
    float s = 0.0f;
    for(int i=0;i<4;i++){ int p = tid + i*64; if(p < Pp) s += fexp2((sc[p]-m)*LOG2E); }
    for(int off=1; off<64; off<<=1) s += __shfl_xor(s, off, 64);
    if(tid == 0){ red[0] = m; red[1] = frcp(s); }
  }
  __syncthreads();
  float mx = red[0], rS = red[1];
  float al_t = 0.0f;
  if(tid < Pp) al_t = fexp2((sc[tid]-mx)*LOG2E) * rS;
  __syncthreads();
  if(tid < Pp) sc[tid] = al_t;
  __syncthreads();
  float c0 = 0.f, c1 = 0.f;
  const unsigned int* fb = (const unsigned int*)(featsB + (size_t)b*Pp*Ee);
  for(int p=0;p<Pp;p++){
    float al = sc[p];
    unsigned int u = fb[(size_t)p*256 + tid];
    unsigned int lo = (u & 0xffffu) << 16, hi = u & 0xffff0000u;
    c0 += al * __builtin_bit_cast(float, lo);
    c1 += al * __builtin_bit_cast(float, hi);
  }
  unsigned int cw = ((unsigned int)f2bf(c1) << 16) | (unsigned int)f2bf(c0);
  scst4((unsigned*)ctx_t + (size_t)b*256 + tid, cw);
}

// hproj via MFMA from staged h: rows R0..R0+15, a-cols HC0..HC0+63
__device__ void hproj_mfma(int R0, int HC0, const char* SMh,
                           const unsigned short* __restrict__ WhT,
                           const float* __restrict__ bhv, float* __restrict__ hpr)
{
  int tid = threadIdx.x;
  int w = tid>>6, l = tid&63, l16 = l&15, lk = l>>4;
  int a = HC0 + w*16 + l16;
  f4 acc = (f4)(0.0f);
  for(int k0=0;k0<512;k0+=32){
    int koff = k0 + lk*8;
    int bo = (l16<<10) + (koff<<1); bo ^= (l16&7)<<4;
    bfrag ah = *(const bfrag*)(SMh + bo);
    bfrag bq = *(const bfrag*)(WhT + (size_t)a*Hh + koff);
    acc = MFMA16(ah, bq, acc);
  }
  float bias = bhv[a];
  #pragma unroll
  for(int i=0;i<4;i++){
    int row = lk*4 + i;
    scstf(hpr + (size_t)(R0+row)*Aa + a, acc[i] + bias);
  }
}

// gates phase A: agh = h@Whh^T, agi = emb@Wih[:,0:512]^T
__device__ void gates_phaseA(int R0, int HC0, const unsigned short* __restrict__ eseqT,
                             const unsigned short* __restrict__ WihB,
                             const unsigned short* __restrict__ WhhB,
                             const char* SMh, f4 (&agh)[3], f4 (&agi)[3])
{
  int tid = threadIdx.x;
  int w = tid>>6, l = tid&63, l16 = l&15, lk = l>>4;
  int hcol = HC0 + w*16 + l16;
  #pragma unroll
  for(int q=0;q<3;q++){ agh[q]=(f4)(0.f); agi[q]=(f4)(0.f); }
  for(int k0=0;k0<512;k0+=32){
    int koff = k0 + lk*8;
    int bo = (l16<<10) + (koff<<1); bo ^= (l16&7)<<4;
    bfrag ah = *(const bfrag*)(SMh + bo);
    bfrag ae = *(const bfrag*)(eseqT + (size_t)(R0+l16)*Ee + koff);
    #pragma unroll
    for(int q=0;q<3;q++){
      int j = q*512 + hcol;
      bfrag bh_ = *(const bfrag*)(WhhB + (size_t)j*512  + koff);
      bfrag be  = *(const bfrag*)(WihB + (size_t)j*1024 + koff);
      agh[q] = MFMA16(ah, bh_, agh[q]);
      agi[q] = MFMA16(ae, be,  agi[q]);
    }
  }
}

// gates phase B: agi += ctx@Wih[:,512:1024]^T; gate math; h_new writes
__device__ void gates_phaseB(int R0, int HC0, const char* SMc,
                             const unsigned short* __restrict__ WihB,
                             const float* __restrict__ bih, const float* __restrict__ bhh,
                             const float* __restrict__ hf_cur, float* __restrict__ hf_nxt,
                             unsigned short* __restrict__ hbU_nxt,
                             f4 (&agh)[3], f4 (&agi)[3], char* SM_HB)
{
  int tid = threadIdx.x;
  int w = tid>>6, l = tid&63, l16 = l&15, lk = l>>4;
  int hcol = HC0 + w*16 + l16;
  for(int k0=0;k0<512;k0+=32){
    int koff = k0 + lk*8;
    int bo = (l16<<10) + (koff<<1); bo ^= (l16&7)<<4;
    bfrag ac = *(const bfrag*)(SMc + bo);
    #pragma unroll
    for(int q=0;q<3;q++){
      int j = q*512 + hcol;
      bfrag bc = *(const bfrag*)(WihB + (size_t)j*1024 + 512 + koff);
      agi[q] = MFMA16(ac, bc, agi[q]);
    }
  }
  float bir = bih[hcol],      bhr = bhh[hcol];
  float biz = bih[512+hcol],  bhz = bhh[512+hcol];
  float bin = bih[1024+hcol], bhn = bhh[1024+hcol];
  unsigned short (*HB)[64] = (unsigned short(*)[64])SM_HB;
  #pragma unroll
  for(int i=0;i<4;i++){
    int row = lk*4 + i;
    int b = R0 + row;
    float r_ = sigm_f(agi[0][i] + bir + agh[0][i] + bhr);
    float z_ = sigm_f(agi[1][i] + biz + agh[1][i] + bhz);
    float n_ = tanh_f(agi[2][i] + bin + r_*(agh[2][i] + bhn));
    float ho = hf_cur[(size_t)b*Hh + hcol];
    float hn = (1.0f - z_)*n_ + z_*ho;
    hf_nxt[(size_t)b*Hh + hcol] = hn;       // block-private slice across steps
    HB[row][w*16 + l16] = f2bf(hn);
  }
  __syncthreads();
  #pragma unroll
  for(int j=0;j<2;j++){
    int widx = tid + j*256;                 // 512 words: 16 rows x 32 word-pairs
    int row = widx >> 5, pr = widx & 31;
    unsigned uu = (unsigned)HB[row][pr*2] | ((unsigned)HB[row][pr*2+1] << 16);
    scst4((unsigned*)(hbU_nxt + (size_t)(R0+row)*Hh + HC0) + pr, uu);
  }
}

// pred tile: 32 b-rows x 256 v-cols; h staged into XOR-swizzled LDS (32 KB)
__device__ void pred_task32(int pt, int tw, const unsigned short* __restrict__ hb_cur,
                            const unsigned short* __restrict__ WoutB,
                            const float* __restrict__ bout, float* __restrict__ out,
                            char* SM)
{
  int tid = threadIdx.x;
  int vchunk = pt >> 2, mbase = (pt & 3)*32;
  #pragma unroll
  for(int j=0;j<16;j++){
    int u = tid + j*256;                  // 4096 8B units
    int row = u >> 7, c8 = u & 127;
    unsigned long long q = scld8(hb_cur + (size_t)(mbase+row)*Hh + c8*4);
    int bo = (row<<10) + (c8<<3);
    bo ^= (row&7)<<4;
    *(unsigned long long*)(SM + bo) = q;
  }
  __syncthreads();
  int w = tid>>6, l = tid&63, l16 = l&15, lk = l>>4;
  int nb = vchunk*256 + w*64;
  f4 acc[2][4];
  #pragma unroll
  for(int mi=0;mi<2;mi++) for(int ni=0;ni<4;ni++) acc[mi][ni] = (f4)(0.0f);
  for(int k0=0;k0<512;k0+=32){
    int koff = k0 + lk*8;
    bfrag af[2], bq[4];
    #pragma unroll
    for(int mi=0;mi<2;mi++){
      int row = mi*16 + l16;
      int bo = (row<<10) + (koff<<1);
      bo ^= (row&7)<<4;
      af[mi] = *(const bfrag*)(SM + bo);
    }
    #pragma unroll
    for(int ni=0;ni<4;ni++){
      int v = nb + ni*16 + l16; if(v > Vv-1) v = Vv-1;
      bq[ni] = *(const bfrag*)(WoutB + (size_t)v*Hh + koff);
    }
    #pragma unroll
    for(int mi=0;mi<2;mi++)
      #pragma unroll
      for(int ni=0;ni<4;ni++)
        acc[mi][ni] = MFMA16(af[mi], bq[ni], acc[mi][ni]);
  }
  #pragma unroll
  for(int ni=0;ni<4;ni++){
    int v = nb + ni*16 + l16;
    if(v < Vv){
      float bias = bout[v];
      #pragma unroll
      for(int mi=0;mi<2;mi++){
        #pragma unroll
        for(int i=0;i<4;i++){
          int br = mbase + mi*16 + lk*4 + i;
          __builtin_nontemporal_store(acc[mi][ni][i] + bias,
              out + (size_t)br*TV + (size_t)tw*Vv + v);
        }
      }
    }
  }
  __syncthreads();
}

// ---------------- the persistent kernel ----------------
// sync lines (64B): [0..31] gbar ctrs, [32] gen, [40..167] flagsA(b),
// [168..231] flagsG(r*8+c), [240..303] flagsP(r*8+c), [304..311] aggP(xcd)
__global__ __launch_bounds__(NTHR, 4) void k_all(
    const float* feats, const int* caps, const float* emb,
    const float* Winh, const float* binh, const float* Wino, const float* bino,
    const float* Wf, const float* bfv, const float* Wh, const float* bhv,
    const float* vatt, const float* Wih, const float* Whh,
    const float* bih, const float* bhh, const float* Wout, const float* bout,
    float* out,
    float* hfR, unsigned short* hbU, float* hpr,
    unsigned short* ctxR, unsigned short* avgB, unsigned short* eseq,
    unsigned short* WfT, unsigned short* WhT,
    unsigned short* WinhT, unsigned short* WinoT,
    unsigned short* WihB, unsigned short* WhhB,
    unsigned short* fpb, unsigned short* featsB, unsigned short* WoutB,
    unsigned* sync)
{
  extern __shared__ char SMEM[];
  const int blk = blockIdx.x, tid = threadIdx.x;
  const int gtid = blk*NTHR + tid;
  unsigned* flagsA = sync + 40*16;
  unsigned* flagsG = sync + 168*16;
  unsigned* flagsP = sync + 240*16;
  unsigned* aggP   = sync + 304*16;
  float* h_f0 = hfR;
  unsigned short* h_b0 = hbU;            // ring slot 0

  // ================= P0 =================
  cast_loop(Wih,  WihB,  (3*Hh*2*Ee)/4, gtid);
  cast_loop(Whh,  WhhB,  (3*Hh*Hh)/4,   gtid);
  cast_loop(Wout, WoutB, (Vv*Hh)/4,     gtid);
  cast_loop(feats,featsB,(Bb*Pp*Ee)/4,  gtid);
  for(int task = blk; task < 1024; task += NBLK){
    int z = task >> 8, rt = task & 255;
    int it = rt & 15, jt = rt >> 4;
    const float* S = (z==0)?Wf:(z==1)?Wh:(z==2)?Winh:Wino;
    unsigned short* D = (z==0)?WfT:(z==1)?WhT:(z==2)?WinhT:WinoT;
    tr_tile(S, D, it, jt, tid, (float(*)[33])SMEM);
  }
  if(blk < Bb){
    int b = blk;
    const float* fb = feats + (size_t)b*Pp*Ee;
    float a0=0.f, a1=0.f;
    for(int p=0;p<Pp;p++){
      float2 v = *(const float2*)(fb + (size_t)p*Ee + tid*2);
      a0 += v.x; a1 += v.y;
    }
    a0 *= (1.0f/Pp); a1 *= (1.0f/Pp);
    unsigned int pack = ((unsigned int)f2bf(a1)<<16) | (unsigned int)f2bf(a0);
    ((unsigned int*)avgB)[(size_t)b*256 + tid] = pack;
  }
  for(int task = blk; task < (Tt-1)*Bb; task += NBLK){
    int ts = task/Bb + 1, b = task%Bb;
    int cap = caps[b*Tt + (ts-1)];
    float2 v = *(const float2*)(emb + (size_t)cap*Ee + tid*2);
    unsigned int pack = ((unsigned int)f2bf(v.y)<<16) | (unsigned int)f2bf(v.x);
    ((unsigned int*)(eseq + ((size_t)ts*Bb + b)*Ee))[tid] = pack;
  }
  gbar2(sync, 1);

  // ================= P1: featproj + initproj =================
  for(int task = blk; task < 1584; task += NBLK){
    int w = tid>>6, l = tid&63, l16 = l&15, lk = l>>4;
    if(task < 1568){
      int bx = task % 196, by = task / 196;
      size_t m_base = (size_t)bx*128 + (w&1)*64;
      int nb = by*64 + (w>>1)*32;
      f4 acc[4][2];
      #pragma unroll
      for(int mi=0;mi<4;mi++) for(int ni=0;ni<2;ni++) acc[mi][ni] = (f4)(0.0f);
      for(int k0=0;k0<512;k0+=32){
        int koff = k0 + lk*8;
        bfrag af[4], bq[2];
        #pragma unroll
        for(int mi=0;mi<4;mi++) af[mi] = *(const bfrag*)(featsB + (m_base+mi*16+l16)*512 + koff);
        #pragma unroll
        for(int ni=0;ni<2;ni++) bq[ni] = *(const bfrag*)(WfT + (size_t)(nb+ni*16+l16)*512 + koff);
        #pragma unroll
        for(int mi=0;mi<4;mi++)
          #pragma unroll
          for(int ni=0;ni<2;ni++)
            acc[mi][ni] = MFMA16(af[mi], bq[ni], acc[mi][ni]);
      }
      #pragma unroll
      for(int ni=0;ni<2;ni++){
        int a = nb + ni*16 + l16;
        float bias = bfv[a];
        #pragma unroll
        for(int mi=0;mi<4;mi++){
          size_t r = m_base + mi*16 + lk*4;
          #pragma unroll
          for(int i=0;i<4;i++)
            fpb[(r+i)*512 + a] = f2bf(acc[mi][ni][i] + bias);
        }
      }
    } else {
      int idx = task - 1568;
      int y = idx >> 3, xb = idx & 7;
      int m0 = (w&1)*64, nb = xb*64 + (w>>1)*32;
      const unsigned short* Wt = y ? WinoT : WinhT;
      const float* bias = y ? bino : binh;
      f4 acc[4][2];
      #pragma unroll
      for(int mi=0;mi<4;mi++) for(int ni=0;ni<2;ni++) acc[mi][ni] = (f4)(0.0f);
      for(int k0=0;k0<512;k0+=32){
        int koff = k0 + lk*8;
        bfrag af[4], bq[2];
        #pragma unroll
        for(int mi=0;mi<4;mi++) af[mi] = *(const bfrag*)(avgB + (size_t)(m0+mi*16+l16)*512 + koff);
        #pragma unroll
        for(int ni=0;ni<2;ni++) bq[ni] = *(const bfrag*)(Wt + (size_t)(nb+ni*16+l16)*512 + koff);
        #pragma unroll
        for(int mi=0;mi<4;mi++)
          #pragma unroll
          for(int ni=0;ni<2;ni++)
            acc[mi][ni] = MFMA16(af[mi], bq[ni], acc[mi][ni]);
      }
      #pragma unroll
      for(int ni=0;ni<2;ni++){
        int n = nb + ni*16 + l16;
        float bv = bias[n];
        #pragma unroll
        for(int mi=0;mi<4;mi++){
          int bb = m0 + mi*16 + lk*4;
          #pragma unroll
          for(int i=0;i<4;i++){
            float val = tanh_f(acc[mi][ni][i] + bv);
            if(y==0){ h_f0[(size_t)(bb+i)*Hh + n] = val; h_b0[(size_t)(bb+i)*Hh + n] = f2bf(val); }
            else    { eseq[(size_t)(bb+i)*Ee + n] = f2bf(val); }
          }
        }
      }
    }
  }
  gbar2(sync, 2);

  // ================= step loop =================
  int xcd = blk & 7, slot = blk >> 3;

  if(slot < 16){
    // ---- attention role: b = slot*8 + xcd ----
    int b = slot*8 + xcd;
    int rg = b >> 4;                       // row group
    for(int t=0; t<Tt; t++){
      poll_flags(flagsP + rg*8*16, 8, (unsigned)(t+1));
      attention_task(b, hpr + (size_t)(t&1)*Bb*Aa, fpb, featsB, vatt,
                     ctxR + (size_t)(t&3)*Bb*Ee, SMEM);
      set_flag(flagsA + b*16, (unsigned)(t+1));
    }
  } else if(slot < 24){
    // ---- gates role: r = slot-16 (rows), c = xcd (cols) ----
    int r = slot - 16, c = xcd;
    int R0 = r*16, HC0 = c*64;
    char* SMh = SMEM;            // 16 KB
    char* SMc = SMEM + 16384;    // 16 KB
    char* SMB = SMEM + 32768;    // HB 2 KB
    f4 agh[3], agi[3];
    stage16(SMh, hbU, R0);                              // h(0) (post-barrier, L3)
    __syncthreads();
    hproj_mfma(R0, HC0, SMh, WhT, bhv, hpr);            // hpr slot 0
    set_flag(flagsP + (r*8+c)*16, 1u);
    gates_phaseA(R0, HC0, eseq, WihB, WhhB, SMh, agh, agi);
    for(int t=0; t<Tt; t++){
      poll_flags(flagsA + R0*16, 16, (unsigned)(t+1));
      stage16(SMc, ctxR + (size_t)(t&3)*Bb*Ee, R0);
      __syncthreads();
      gates_phaseB(R0, HC0, SMc, WihB, bih, bhh,
                   hfR + (size_t)(t&1)*Bb*Hh, hfR + (size_t)((t+1)&1)*Bb*Hh,
                   hbU + (size_t)(t+1)*Bb*Hh, agh, agi, SMB);
      set_flag(flagsG + (r*8+c)*16, (unsigned)(t+1));
      if(t+1 < Tt){
        poll_flags(flagsG + r*8*16, 8, (unsigned)(t+1));
        stage16(SMh, hbU + (size_t)(t+1)*Bb*Hh, R0);
        __syncthreads();
        hproj_mfma(R0, HC0, SMh, WhT, bhv, hpr + (size_t)((t+1)&1)*Bb*Aa);
        set_flag(flagsP + (r*8+c)*16, (unsigned)(t+2));
        gates_phaseA(R0, HC0, eseq + (size_t)(t+1)*Bb*Ee, WihB, WhhB, SMh, agh, agi);
      }
    }
  } else {
    // ---- pred role: 32x256 tiles, one per block ----
    int ps = slot - 24;                    // 0..39
    int pt = xcd*40 + ps;
    if(ps == 0){
      for(int t=1; t<=Tt; t++){
        poll_flags(flagsG, 64, (unsigned)t);
        if(tid == 0) scst4(aggP + xcd*16, (unsigned)t);
        pred_task32(pt, t-1, hbU + (size_t)t*Bb*Hh, WoutB, bout, out, SMEM);
      }
    } else if(pt < 316){
      for(int t=1; t<=Tt; t++){
        poll_flags(aggP + xcd*16, 1, (unsigned)t);
        pred_task32(pt, t-1, hbU + (size_t)t*Bb*Hh, WoutB, bout, out, SMEM);
      }
    }
  }
}

extern "C" void kernel_launch(void* const* d_in, const int* in_sizes, int n_in,
                              void* d_out, int out_size, void* d_ws, size_t ws_size,
                              hipStream_t stream)
{
  const float* feats = (const float*)d_in[0];
  const int*   caps  = (const int*)d_in[1];
  const float* emb   = (const float*)d_in[2];
  const float* Winh  = (const float*)d_in[3];
  const float* binh  = (const float*)d_in[4];
  const float* Wino  = (const float*)d_in[5];
  const float* bino  = (const float*)d_in[6];
  const float* Wf    = (const float*)d_in[7];
  const float* bfv   = (const float*)d_in[8];
  const float* Wh    = (const float*)d_in[9];
  const float* bhv   = (const float*)d_in[10];
  const float* vatt  = (const float*)d_in[11];
  const float* Wih   = (const float*)d_in[12];
  const float* Whh   = (const float*)d_in[13];
  const float* bih   = (const float*)d_in[14];
  const float* bhh   = (const float*)d_in[15];
  const float* Wout  = (const float*)d_in[16];
  const float* bout  = (const float*)d_in[17];
  float* out = (float*)d_out;

  char* ws = (char*)d_ws;
  size_t off = 0;
  auto alloc = [&](size_t bytes){
    off = (off + 255) & ~(size_t)255;
    void* p = ws + off; off += bytes; return p;
  };
  unsigned* syncp = (unsigned*)alloc(32768);
  float* hfR = (float*)alloc((size_t)2*Bb*Hh*4);                        // hf ring (2)
  unsigned short* hbU = (unsigned short*)alloc((size_t)(Tt+1)*Bb*Hh*2); // h ring (25)
  float* hpr = (float*)alloc((size_t)2*Bb*Aa*4);                        // hproj ring (2)
  unsigned short* ctxR  = (unsigned short*)alloc((size_t)4*Bb*Ee*2);    // ctx ring (4)
  unsigned short* avgB  = (unsigned short*)alloc((size_t)Bb*Ee*2);
  unsigned short* eseq  = (unsigned short*)alloc((size_t)Tt*Bb*Ee*2);
  unsigned short* WfT   = (unsigned short*)alloc((size_t)Ee*Aa*2);
  unsigned short* WhT   = (unsigned short*)alloc((size_t)Hh*Aa*2);
  unsigned short* WinhT = (unsigned short*)alloc((size_t)Ee*Hh*2);
  unsigned short* WinoT = (unsigned short*)alloc((size_t)Ee*Hh*2);
  unsigned short* WihB  = (unsigned short*)alloc((size_t)3*Hh*2*Ee*2);
  unsigned short* WhhB  = (unsigned short*)alloc((size_t)3*Hh*Hh*2);
  unsigned short* fpb   = (unsigned short*)alloc((size_t)Bb*Pp*Aa*2);
  unsigned short* featsB= (unsigned short*)alloc((size_t)Bb*Pp*Ee*2);
  unsigned short* WoutB = (unsigned short*)alloc((size_t)Vv*Hh*2);
  if(ws_size < off) return;   // diagnostic no-op

  k_zero<<<32, 256, 0, stream>>>(syncp);
  k_all<<<NBLK, NTHR, SMEM_BYTES, stream>>>(
      feats, caps, emb, Winh, binh, Wino, bino, Wf, bfv, Wh, bhv, vatt,
      Wih, Whh, bih, bhh, Wout, bout, out,
      hfR, hbU, hpr, ctxR, avgB, eseq,
      WfT, WhT, WinhT, WinoT, WihB, WhhB, fpb, featsB, WoutB, syncp);
}